// Round 7
// baseline (177.661 us; speedup 1.0000x reference)
//
#include <hip/hip_runtime.h>
#include <hip/hip_bf16.h>

#define S_LEN 8192
#define E_DIM 64
#define NCONV (63 * 8191)
#define SVT (S_LEN + 32)   // vT_bf row stride (shorts): breaks L1 set aliasing
#define KTS 72             // kt LDS row stride (shorts)
#define VTS 40             // vt LDS row stride (shorts)
#define PS  40             // pT LDS row stride (shorts)

typedef short short8 __attribute__((ext_vector_type(8)));
typedef float f32x4 __attribute__((ext_vector_type(4)));

__device__ __forceinline__ float ldin(const void* __restrict__ p, int i, int f32flag) {
    return f32flag ? ((const float*)p)[i]
                   : __bfloat162float(((const __hip_bfloat16*)p)[i]);
}
__device__ __forceinline__ float bfbits2f(unsigned int u16bits) {
    union { unsigned int u; float f; } c; c.u = u16bits << 16; return c.f;
}
__device__ __forceinline__ unsigned short f2bfu(float f) {
    __hip_bfloat16 h = __float2bfloat16(f);
    union { __hip_bfloat16 h; unsigned short u; } c; c.h = h; return c.u;
}
__device__ __forceinline__ int hw_bad(unsigned short h) {
    const unsigned int e = (h >> 7) & 0xFF;
    return !(h == 0 || h == 0x8000 || (e >= 0x60 && e <= 0x86));
}

// ---------------- Kernel 1: fused QKV projection + conv reduction ----------------
// blocks 0..511: qkv for 16 rows each. blocks 512..575: conv partial sums.
__global__ __launch_bounds__(256) void qkv_conv(
    const void* __restrict__ x,
    const void* __restrict__ conv_w, const void* __restrict__ conv_b,
    const void* __restrict__ Wq, const void* __restrict__ bq,
    const void* __restrict__ Wk, const void* __restrict__ bk,
    const void* __restrict__ Wv, const void* __restrict__ bv,
    unsigned short* __restrict__ q_bf, unsigned short* __restrict__ k_bf,
    unsigned short* __restrict__ vT_bf, float* __restrict__ conv_part)
{
    __shared__ int s_fx, s_fw;
    const int tid = threadIdx.x;
    if (tid == 0) { s_fx = 0; s_fw = 0; }
    __syncthreads();
    if (tid < 64) { if (hw_bad(((const unsigned short*)x)[tid])) atomicOr(&s_fx, 1); }
    else if (tid < 128) { if (hw_bad(((const unsigned short*)Wq)[tid - 64])) atomicOr(&s_fw, 1); }
    __syncthreads();
    const int fx = s_fx, fw = s_fw;

    if (blockIdx.x >= 512) {   // ---- conv path ----
        const int bid = blockIdx.x - 512;
        const float c0 = ldin(conv_w, 0, fw), c1 = ldin(conv_w, 1, fw);
        const float c2 = ldin(conv_w, 2, fw), c3 = ldin(conv_w, 3, fw);
        const float cb = ldin(conv_b, 0, fw);
        float acc = 0.f;
        for (int idx = bid * 256 + tid; idx < NCONV; idx += 64 * 256) {
            const int h = idx % 63;
            const int w = idx / 63;
            const float z = c0 * ldin(x, w * 64 + h, fx)     + c1 * ldin(x, (w + 1) * 64 + h, fx)
                          + c2 * ldin(x, w * 64 + h + 1, fx) + c3 * ldin(x, (w + 1) * 64 + h + 1, fx)
                          + cb;
            acc += 1.f / (1.f + __expf(-z));
        }
        for (int off = 32; off > 0; off >>= 1) acc += __shfl_down(acc, off);
        __shared__ float wsum[4];
        if ((tid & 63) == 0) wsum[tid >> 6] = acc;
        __syncthreads();
        if (tid == 0) conv_part[bid] = wsum[0] + wsum[1] + wsum[2] + wsum[3];
        return;
    }

    // ---- qkv path (verified R4-R6) ----
    __shared__ float wsh[3][4096];
    __shared__ float xT[64 * 16];
    __shared__ float bsh[3][64];
    __shared__ float vs[64 * 17];
    const int row0 = blockIdx.x * 16;
    const void* Ws[3] = { Wq, Wk, Wv };
    const void* Bs[3] = { bq, bk, bv };
#pragma unroll
    for (int w = 0; w < 3; ++w) {
        if (fw) {
            const float4* src = (const float4*)Ws[w];
            for (int i = tid; i < 1024; i += 256) {
                float4 v = src[i];
                float* d = &wsh[w][i * 4];
                d[0] = v.x; d[1] = v.y; d[2] = v.z; d[3] = v.w;
            }
            if (tid < 64) bsh[w][tid] = ((const float*)Bs[w])[tid];
        } else {
            const uint4* src = (const uint4*)Ws[w];
            for (int i = tid; i < 512; i += 256) {
                uint4 v = src[i];
                float* d = &wsh[w][i * 8];
                d[0] = bfbits2f(v.x & 0xffff); d[1] = bfbits2f(v.x >> 16);
                d[2] = bfbits2f(v.y & 0xffff); d[3] = bfbits2f(v.y >> 16);
                d[4] = bfbits2f(v.z & 0xffff); d[5] = bfbits2f(v.z >> 16);
                d[6] = bfbits2f(v.w & 0xffff); d[7] = bfbits2f(v.w >> 16);
            }
            if (tid < 64) bsh[w][tid] = bfbits2f(((const unsigned short*)Bs[w])[tid]);
        }
    }
    for (int idx = tid; idx < 1024; idx += 256) {
        const int r = idx >> 6, i = idx & 63;
        xT[i * 16 + r] = ldin(x, (row0 + r) * 64 + i, fx);
    }
    __syncthreads();

    const int e = tid & 63, rg = tid >> 6;
    float aq[4], ak[4], av[4];
#pragma unroll
    for (int r = 0; r < 4; ++r) { aq[r] = bsh[0][e]; ak[r] = bsh[1][e]; av[r] = bsh[2][e]; }
#pragma unroll 8
    for (int i = 0; i < 64; ++i) {
        const float4 xv = *(const float4*)&xT[i * 16 + rg * 4];
        const float wq = wsh[0][i * 64 + e], wk = wsh[1][i * 64 + e], wv = wsh[2][i * 64 + e];
        aq[0] += xv.x * wq; aq[1] += xv.y * wq; aq[2] += xv.z * wq; aq[3] += xv.w * wq;
        ak[0] += xv.x * wk; ak[1] += xv.y * wk; ak[2] += xv.z * wk; ak[3] += xv.w * wk;
        av[0] += xv.x * wv; av[1] += xv.y * wv; av[2] += xv.z * wv; av[3] += xv.w * wv;
    }
#pragma unroll
    for (int r = 0; r < 4; ++r) {
        const int row = row0 + rg * 4 + r;
        q_bf[row * 64 + e] = f2bfu(aq[r]);
        k_bf[row * 64 + e] = f2bfu(ak[r]);
        vs[e * 17 + rg * 4 + r] = av[r];
    }
    __syncthreads();
    {
        const int e2 = tid >> 2, rp = (tid & 3) * 4;
        const unsigned short h0 = f2bfu(vs[e2 * 17 + rp + 0]);
        const unsigned short h1 = f2bfu(vs[e2 * 17 + rp + 1]);
        const unsigned short h2 = f2bfu(vs[e2 * 17 + rp + 2]);
        const unsigned short h3 = f2bfu(vs[e2 * 17 + rp + 3]);
        uint2 pk;
        pk.x = (unsigned int)h0 | ((unsigned int)h1 << 16);
        pk.y = (unsigned int)h2 | ((unsigned int)h3 << 16);
        *(uint2*)(vT_bf + (size_t)e2 * SVT + row0 + rp) = pk;
    }
}

// ---------------- Kernel 2: MFMA flash attention, LDS-staged K/V, 4 Q-tiles/wave ----------------
// Block: 4 waves x 64 q-rows = 256 rows. Per 32-key iter: K/V tiles staged to LDS
// (double-buffered, prefetch overlaps compute), shared by all waves.
// Even/odd key interleave packs P-writes into conflict-free u32 stores.
__global__ __launch_bounds__(256) void attn_bf(
    const unsigned short* __restrict__ q_bf, const unsigned short* __restrict__ k_bf,
    const unsigned short* __restrict__ vT_bf,
    unsigned short* __restrict__ o_split, float* __restrict__ l_split, int krange)
{
    __shared__ unsigned short kt[2][32 * KTS];    //  9216 B
    __shared__ unsigned short vt[2][64 * VTS];    // 10240 B
    __shared__ unsigned short pTs[4][4][16 * PS]; // 20480 B
    const int tid = threadIdx.x;
    const int wave = tid >> 6, lane = tid & 63;
    const int ln = lane & 15, quad = lane >> 4;
    const int qrow0 = blockIdx.x * 256 + wave * 64;
    const int kbase = blockIdx.y * krange;

    // Q A-fragments for 4 tiles x 2 E-halves
    short8 aQ[4][2];
#pragma unroll
    for (int T = 0; T < 4; ++T) {
        aQ[T][0] = *(const short8*)(q_bf + (qrow0 + 16 * T + ln) * 64 + quad * 8);
        aQ[T][1] = *(const short8*)(q_bf + (qrow0 + 16 * T + ln) * 64 + 32 + quad * 8);
    }

    const f32x4 zero = {0.f, 0.f, 0.f, 0.f};
    f32x4 acc[4][4];
    float l_acc[4][4];
#pragma unroll
    for (int T = 0; T < 4; ++T)
#pragma unroll
        for (int n = 0; n < 4; ++n) { acc[T][n] = zero; l_acc[T][n] = 0.f; }

    // staging thread roles
    const int krow = tid >> 3, kch = tid & 7;   // K: 32 rows x 8 chunks
    const int vrow = tid >> 2, vch = tid & 3;   // V: 64 rows x 4 chunks
    uint4 kreg, vreg;

    kreg = *(const uint4*)(k_bf + (size_t)(kbase + krow) * 64 + kch * 8);
    vreg = *(const uint4*)(vT_bf + (size_t)vrow * SVT + kbase + vch * 8);
    *(uint4*)(&kt[0][krow * KTS + kch * 8]) = kreg;
    *(uint4*)(&vt[0][vrow * VTS + vch * 8]) = vreg;
    __syncthreads();

    const int nIter = krange >> 5;
#pragma unroll 2
    for (int kc = 0; kc < nIter; ++kc) {
        const int cur = kc & 1;
        if (kc + 1 < nIter) {   // prefetch next tile into registers (overlaps compute)
            const int key1 = kbase + (kc + 1) * 32;
            kreg = *(const uint4*)(k_bf + (size_t)(key1 + krow) * 64 + kch * 8);
            vreg = *(const uint4*)(vT_bf + (size_t)vrow * SVT + key1 + vch * 8);
        }
        const unsigned short* ktc = &kt[cur][0];
        const unsigned short* vtc = &vt[cur][0];
        // K B-frags: even keys (2ln) and odd keys (2ln+1), two E-halves each
        const short8 bE0 = *(const short8*)(ktc + (2 * ln) * KTS + quad * 8);
        const short8 bE1 = *(const short8*)(ktc + (2 * ln) * KTS + 32 + quad * 8);
        const short8 bO0 = *(const short8*)(ktc + (2 * ln + 1) * KTS + quad * 8);
        const short8 bO1 = *(const short8*)(ktc + (2 * ln + 1) * KTS + 32 + quad * 8);
        // V B-frags (actual key order)
        const short8 v0 = *(const short8*)(vtc + (0 * 16 + ln) * VTS + quad * 8);
        const short8 v1 = *(const short8*)(vtc + (1 * 16 + ln) * VTS + quad * 8);
        const short8 v2 = *(const short8*)(vtc + (2 * 16 + ln) * VTS + quad * 8);
        const short8 v3 = *(const short8*)(vtc + (3 * 16 + ln) * VTS + quad * 8);

        f32x4 scE[4], scO[4];
#pragma unroll
        for (int T = 0; T < 4; ++T) {
            scE[T] = __builtin_amdgcn_mfma_f32_16x16x32_bf16(aQ[T][0], bE0, zero, 0, 0, 0);
            scE[T] = __builtin_amdgcn_mfma_f32_16x16x32_bf16(aQ[T][1], bE1, scE[T], 0, 0, 0);
            scO[T] = __builtin_amdgcn_mfma_f32_16x16x32_bf16(aQ[T][0], bO0, zero, 0, 0, 0);
            scO[T] = __builtin_amdgcn_mfma_f32_16x16x32_bf16(aQ[T][1], bO1, scO[T], 0, 0, 0);
        }
        // exp (bounded scores, no max-sub), pack (even,odd) -> u32, conflict-free write
#pragma unroll
        for (int T = 0; T < 4; ++T) {
            unsigned short* w = &pTs[wave][T][0];
#pragma unroll
            for (int r = 0; r < 4; ++r) {
                const float pE = __expf(scE[T][r] * 0.125f);
                const float pO = __expf(scO[T][r] * 0.125f);
                l_acc[T][r] += pE + pO;
                const unsigned int pk = (unsigned int)f2bfu(pE) | ((unsigned int)f2bfu(pO) << 16);
                *(unsigned int*)(w + (quad * 4 + r) * PS + 2 * ln) = pk;
            }
        }
        // PV (wave-synchronous pT read; compiler inserts lgkmcnt wait)
#pragma unroll
        for (int T = 0; T < 4; ++T) {
            const short8 aP = *(const short8*)(&pTs[wave][T][ln * PS + quad * 8]);
            acc[T][0] = __builtin_amdgcn_mfma_f32_16x16x32_bf16(aP, v0, acc[T][0], 0, 0, 0);
            acc[T][1] = __builtin_amdgcn_mfma_f32_16x16x32_bf16(aP, v1, acc[T][1], 0, 0, 0);
            acc[T][2] = __builtin_amdgcn_mfma_f32_16x16x32_bf16(aP, v2, acc[T][2], 0, 0, 0);
            acc[T][3] = __builtin_amdgcn_mfma_f32_16x16x32_bf16(aP, v3, acc[T][3], 0, 0, 0);
        }
        __syncthreads();
        if (kc + 1 < nIter) {
            *(uint4*)(&kt[cur ^ 1][krow * KTS + kch * 8]) = kreg;
            *(uint4*)(&vt[cur ^ 1][vrow * VTS + vch * 8]) = vreg;
        }
        __syncthreads();
    }

    // epilogue: bf16 partial o + l per split
    unsigned short* ob = o_split + ((size_t)blockIdx.y * S_LEN + qrow0) * 64;
#pragma unroll
    for (int T = 0; T < 4; ++T) {
#pragma unroll
        for (int r = 0; r < 4; ++r) {
            const int row = 16 * T + quad * 4 + r;
            ob[row * 64 +  0 + ln] = f2bfu(acc[T][0][r]);
            ob[row * 64 + 16 + ln] = f2bfu(acc[T][1][r]);
            ob[row * 64 + 32 + ln] = f2bfu(acc[T][2][r]);
            ob[row * 64 + 48 + ln] = f2bfu(acc[T][3][r]);
        }
#pragma unroll
        for (int r = 0; r < 4; ++r) {
            float v = l_acc[T][r];
            v += __shfl_xor(v, 1); v += __shfl_xor(v, 2);
            v += __shfl_xor(v, 4); v += __shfl_xor(v, 8);
            if (ln == 0)
                l_split[blockIdx.y * S_LEN + qrow0 + 16 * T + quad * 4 + r] = v;
        }
    }
}

// ---------------- Kernel 3: fused normalize + pool + finalize (last-block-done) ----------------
__global__ __launch_bounds__(256) void norm_final(
    const unsigned short* __restrict__ o_split, const float* __restrict__ l_split,
    float* __restrict__ g_pooled, int* __restrict__ counter,
    const float* __restrict__ conv_part,
    const void* __restrict__ Wp, const void* __restrict__ bp,
    const void* __restrict__ x, const void* __restrict__ Wq,
    void* __restrict__ out, int ksplit)
{
    __shared__ float psh[64];
    const int tid = threadIdx.x;
    if (tid < 64) psh[tid] = 0.f;
    __syncthreads();
#pragma unroll
    for (int rr = 0; rr < 4; ++rr) {
        const int r = blockIdx.x * 128 + rr * 32 + (tid >> 3);
        const int c = (tid & 7) * 8;
        float l = 0.f;
        for (int s = 0; s < ksplit; ++s) l += l_split[s * S_LEN + r];
        float o[8] = {0.f, 0.f, 0.f, 0.f, 0.f, 0.f, 0.f, 0.f};
        for (int s = 0; s < ksplit; ++s) {
            const uint4 v = *(const uint4*)(o_split + ((size_t)s * S_LEN + r) * 64 + c);
            o[0] += bfbits2f(v.x & 0xffff); o[1] += bfbits2f(v.x >> 16);
            o[2] += bfbits2f(v.y & 0xffff); o[3] += bfbits2f(v.y >> 16);
            o[4] += bfbits2f(v.z & 0xffff); o[5] += bfbits2f(v.z >> 16);
            o[6] += bfbits2f(v.w & 0xffff); o[7] += bfbits2f(v.w >> 16);
        }
        const float inv = 1.f / l;
#pragma unroll
        for (int j = 0; j < 8; ++j) atomicAdd(&psh[c + j], o[j] * inv);
    }
    __syncthreads();
    if (tid < 64) atomicAdd(&g_pooled[tid], psh[tid]);
    __threadfence();
    __shared__ int s_last;
    if (tid == 0) s_last = (atomicAdd(counter, 1) == 63) ? 1 : 0;
    __syncthreads();
    if (!s_last || tid >= 64) return;

    // final projection (one wave of the last block)
    __threadfence();
    const int e = tid;
    int badx = hw_bad(((const unsigned short*)x)[e]);
    int badw = hw_bad(((const unsigned short*)Wq)[e]);
    const int fx = (__ballot(badx) != 0ULL) ? 1 : 0;
    const int fw = (__ballot(badw) != 0ULL) ? 1 : 0;
    const int out_f32 = fx & fw;

    float cv = conv_part[e];
    cv += __shfl_xor(cv, 1); cv += __shfl_xor(cv, 2); cv += __shfl_xor(cv, 4);
    cv += __shfl_xor(cv, 8); cv += __shfl_xor(cv, 16); cv += __shfl_xor(cv, 32);
    const float conv_feat = cv * (1.f / (float)NCONV);
    const float pe = atomicAdd(&g_pooled[e], 0.f);   // coherent read
    const float pooled = pe * (1.f / (float)S_LEN) * conv_feat;
    float p0 = pooled * ldin(Wp, e * 4 + 0, fw);
    float p1 = pooled * ldin(Wp, e * 4 + 1, fw);
    float p2 = pooled * ldin(Wp, e * 4 + 2, fw);
    float p3 = pooled * ldin(Wp, e * 4 + 3, fw);
    for (int off = 32; off > 0; off >>= 1) {
        p0 += __shfl_down(p0, off);
        p1 += __shfl_down(p1, off);
        p2 += __shfl_down(p2, off);
        p3 += __shfl_down(p3, off);
    }
    if (e == 0) {
        const float r0 = p0 + ldin(bp, 0, fw);
        const float r1 = p1 + ldin(bp, 1, fw);
        const float r2 = p2 + ldin(bp, 2, fw);
        const float r3 = p3 + ldin(bp, 3, fw);
        if (out_f32) {
            float* o = (float*)out;
            o[0] = r0; o[1] = r1; o[2] = r2; o[3] = r3;
        } else {
            __hip_bfloat16* o = (__hip_bfloat16*)out;
            o[0] = __float2bfloat16(r0); o[1] = __float2bfloat16(r1);
            o[2] = __float2bfloat16(r2); o[3] = __float2bfloat16(r3);
        }
    }
}

extern "C" void kernel_launch(void* const* d_in, const int* in_sizes, int n_in,
                              void* d_out, int out_size, void* d_ws, size_t ws_size,
                              hipStream_t stream)
{
    const void* x  = d_in[0];
    const void* cw = d_in[1];
    const void* cb = d_in[2];
    const void* Wq = d_in[3];
    const void* bq = d_in[4];
    const void* Wk = d_in[5];
    const void* bk = d_in[6];
    const void* Wv = d_in[7];
    const void* bv = d_in[8];
    const void* Wp = d_in[9];
    const void* bp = d_in[10];

    auto need = [](int ks) -> size_t {
        return (256 + (size_t)ks * S_LEN) * 4
             + (size_t)ks * S_LEN * 64 * 2
             + 2 * (size_t)S_LEN * 64 * 2 + (size_t)64 * SVT * 2 + 1024;
    };
    int ksplit = (ws_size >= need(16)) ? 16 : 8;

    float* ws = (float*)d_ws;
    float* g_pooled  = ws;                       // 64 f32
    int*   counter   = (int*)(ws + 64);          // 1 int
    float* conv_part = ws + 128;                 // 64 f32
    float* l_split   = ws + 256;                 // ks*S f32
    unsigned short* o_split = (unsigned short*)(l_split + (size_t)ksplit * S_LEN);
    unsigned short* q_bf  = o_split + (size_t)ksplit * S_LEN * 64;
    unsigned short* k_bf  = q_bf + (size_t)S_LEN * 64;
    unsigned short* vT_bf = k_bf + (size_t)S_LEN * 64;

    hipMemsetAsync(d_ws, 0, 512, stream);   // zero g_pooled + counter
    qkv_conv<<<576, 256, 0, stream>>>(x, cw, cb, Wq, bq, Wk, bk, Wv, bv,
                                      q_bf, k_bf, vT_bf, conv_part);
    attn_bf<<<dim3(S_LEN / 256, ksplit), 256, 0, stream>>>(q_bf, k_bf, vT_bf, o_split, l_split,
                                                            S_LEN / ksplit);
    norm_final<<<64, 256, 0, stream>>>(o_split, l_split, g_pooled, counter, conv_part,
                                       Wp, bp, x, Wq, d_out, ksplit);
}

// Round 8
// 171.993 us; speedup vs baseline: 1.0330x; 1.0330x over previous
//
#include <hip/hip_runtime.h>
#include <hip/hip_bf16.h>

#define S_LEN 8192
#define E_DIM 64
#define NCONV (63 * 8191)
#define SVT (S_LEN + 32)   // vT_bf row stride (shorts): breaks L1 set aliasing
#define KTS 72             // kt LDS row stride (shorts)
#define VTS 40             // vt LDS row stride (shorts)
#define PS  40             // pT LDS row stride (shorts)

typedef short short8 __attribute__((ext_vector_type(8)));
typedef float f32x4 __attribute__((ext_vector_type(4)));

__device__ __forceinline__ float ldin(const void* __restrict__ p, int i, int f32flag) {
    return f32flag ? ((const float*)p)[i]
                   : __bfloat162float(((const __hip_bfloat16*)p)[i]);
}
__device__ __forceinline__ float bfbits2f(unsigned int u16bits) {
    union { unsigned int u; float f; } c; c.u = u16bits << 16; return c.f;
}
__device__ __forceinline__ unsigned short f2bfu(float f) {
    __hip_bfloat16 h = __float2bfloat16(f);
    union { __hip_bfloat16 h; unsigned short u; } c; c.h = h; return c.u;
}
__device__ __forceinline__ int hw_bad(unsigned short h) {
    const unsigned int e = (h >> 7) & 0xFF;
    return !(h == 0 || h == 0x8000 || (e >= 0x60 && e <= 0x86));
}

// ---------------- Kernel 1: fused QKV projection + conv reduction + counter init ----------------
// blocks 0..511: qkv for 16 rows each. blocks 512..575: conv partial sums.
__global__ __launch_bounds__(256) void qkv_conv(
    const void* __restrict__ x,
    const void* __restrict__ conv_w, const void* __restrict__ conv_b,
    const void* __restrict__ Wq, const void* __restrict__ bq,
    const void* __restrict__ Wk, const void* __restrict__ bk,
    const void* __restrict__ Wv, const void* __restrict__ bv,
    unsigned short* __restrict__ q_bf, unsigned short* __restrict__ k_bf,
    unsigned short* __restrict__ vT_bf, float* __restrict__ conv_part,
    int* __restrict__ counter)
{
    __shared__ int s_fx, s_fw;
    const int tid = threadIdx.x;
    if (tid == 0) { s_fx = 0; s_fw = 0; }
    __syncthreads();
    if (tid < 64) { if (hw_bad(((const unsigned short*)x)[tid])) atomicOr(&s_fx, 1); }
    else if (tid < 128) { if (hw_bad(((const unsigned short*)Wq)[tid - 64])) atomicOr(&s_fw, 1); }
    __syncthreads();
    const int fx = s_fx, fw = s_fw;

    if (blockIdx.x >= 512) {   // ---- conv path ----
        const int bid = blockIdx.x - 512;
        if (bid == 0 && tid == 0) *counter = 0;   // init for norm_final (stream-ordered)
        const float c0 = ldin(conv_w, 0, fw), c1 = ldin(conv_w, 1, fw);
        const float c2 = ldin(conv_w, 2, fw), c3 = ldin(conv_w, 3, fw);
        const float cb = ldin(conv_b, 0, fw);
        float acc = 0.f;
        for (int idx = bid * 256 + tid; idx < NCONV; idx += 64 * 256) {
            const int h = idx % 63;
            const int w = idx / 63;
            const float z = c0 * ldin(x, w * 64 + h, fx)     + c1 * ldin(x, (w + 1) * 64 + h, fx)
                          + c2 * ldin(x, w * 64 + h + 1, fx) + c3 * ldin(x, (w + 1) * 64 + h + 1, fx)
                          + cb;
            acc += 1.f / (1.f + __expf(-z));
        }
        for (int off = 32; off > 0; off >>= 1) acc += __shfl_down(acc, off);
        __shared__ float wsum[4];
        if ((tid & 63) == 0) wsum[tid >> 6] = acc;
        __syncthreads();
        if (tid == 0) conv_part[bid] = wsum[0] + wsum[1] + wsum[2] + wsum[3];
        return;
    }

    // ---- qkv path (verified R4-R7) ----
    __shared__ float wsh[3][4096];
    __shared__ float xT[64 * 16];
    __shared__ float bsh[3][64];
    __shared__ float vs[64 * 17];
    const int row0 = blockIdx.x * 16;
    const void* Ws[3] = { Wq, Wk, Wv };
    const void* Bs[3] = { bq, bk, bv };
#pragma unroll
    for (int w = 0; w < 3; ++w) {
        if (fw) {
            const float4* src = (const float4*)Ws[w];
            for (int i = tid; i < 1024; i += 256) {
                float4 v = src[i];
                float* d = &wsh[w][i * 4];
                d[0] = v.x; d[1] = v.y; d[2] = v.z; d[3] = v.w;
            }
            if (tid < 64) bsh[w][tid] = ((const float*)Bs[w])[tid];
        } else {
            const uint4* src = (const uint4*)Ws[w];
            for (int i = tid; i < 512; i += 256) {
                uint4 v = src[i];
                float* d = &wsh[w][i * 8];
                d[0] = bfbits2f(v.x & 0xffff); d[1] = bfbits2f(v.x >> 16);
                d[2] = bfbits2f(v.y & 0xffff); d[3] = bfbits2f(v.y >> 16);
                d[4] = bfbits2f(v.z & 0xffff); d[5] = bfbits2f(v.z >> 16);
                d[6] = bfbits2f(v.w & 0xffff); d[7] = bfbits2f(v.w >> 16);
            }
            if (tid < 64) bsh[w][tid] = bfbits2f(((const unsigned short*)Bs[w])[tid]);
        }
    }
    for (int idx = tid; idx < 1024; idx += 256) {
        const int r = idx >> 6, i = idx & 63;
        xT[i * 16 + r] = ldin(x, (row0 + r) * 64 + i, fx);
    }
    __syncthreads();

    const int e = tid & 63, rg = tid >> 6;
    float aq[4], ak[4], av[4];
#pragma unroll
    for (int r = 0; r < 4; ++r) { aq[r] = bsh[0][e]; ak[r] = bsh[1][e]; av[r] = bsh[2][e]; }
#pragma unroll 8
    for (int i = 0; i < 64; ++i) {
        const float4 xv = *(const float4*)&xT[i * 16 + rg * 4];
        const float wq = wsh[0][i * 64 + e], wk = wsh[1][i * 64 + e], wv = wsh[2][i * 64 + e];
        aq[0] += xv.x * wq; aq[1] += xv.y * wq; aq[2] += xv.z * wq; aq[3] += xv.w * wq;
        ak[0] += xv.x * wk; ak[1] += xv.y * wk; ak[2] += xv.z * wk; ak[3] += xv.w * wk;
        av[0] += xv.x * wv; av[1] += xv.y * wv; av[2] += xv.z * wv; av[3] += xv.w * wv;
    }
#pragma unroll
    for (int r = 0; r < 4; ++r) {
        const int row = row0 + rg * 4 + r;
        q_bf[row * 64 + e] = f2bfu(aq[r]);
        k_bf[row * 64 + e] = f2bfu(ak[r]);
        vs[e * 17 + rg * 4 + r] = av[r];
    }
    __syncthreads();
    {
        const int e2 = tid >> 2, rp = (tid & 3) * 4;
        const unsigned short h0 = f2bfu(vs[e2 * 17 + rp + 0]);
        const unsigned short h1 = f2bfu(vs[e2 * 17 + rp + 1]);
        const unsigned short h2 = f2bfu(vs[e2 * 17 + rp + 2]);
        const unsigned short h3 = f2bfu(vs[e2 * 17 + rp + 3]);
        uint2 pk;
        pk.x = (unsigned int)h0 | ((unsigned int)h1 << 16);
        pk.y = (unsigned int)h2 | ((unsigned int)h3 << 16);
        *(uint2*)(vT_bf + (size_t)e2 * SVT + row0 + rp) = pk;
    }
}

// ---------------- Kernel 2: MFMA flash attention, LDS dbuf (1 barrier/iter), 4 Q-tiles/wave ----------------
__global__ __launch_bounds__(256) void attn_bf(
    const unsigned short* __restrict__ q_bf, const unsigned short* __restrict__ k_bf,
    const unsigned short* __restrict__ vT_bf,
    unsigned short* __restrict__ o_split, float* __restrict__ l_split, int krange)
{
    __shared__ unsigned short kt[2][32 * KTS];    //  9216 B
    __shared__ unsigned short vt[2][64 * VTS];    // 10240 B
    __shared__ unsigned short pTs[4][4][16 * PS]; // 20480 B
    const int tid = threadIdx.x;
    const int wave = tid >> 6, lane = tid & 63;
    const int ln = lane & 15, quad = lane >> 4;
    const int qrow0 = blockIdx.x * 256 + wave * 64;
    const int kbase = blockIdx.y * krange;

    short8 aQ[4][2];
#pragma unroll
    for (int T = 0; T < 4; ++T) {
        aQ[T][0] = *(const short8*)(q_bf + (qrow0 + 16 * T + ln) * 64 + quad * 8);
        aQ[T][1] = *(const short8*)(q_bf + (qrow0 + 16 * T + ln) * 64 + 32 + quad * 8);
    }

    const f32x4 zero = {0.f, 0.f, 0.f, 0.f};
    f32x4 acc[4][4];
    float l_acc[4][4];
#pragma unroll
    for (int T = 0; T < 4; ++T)
#pragma unroll
        for (int n = 0; n < 4; ++n) { acc[T][n] = zero; l_acc[T][n] = 0.f; }

    const int krow = tid >> 3, kch = tid & 7;   // K: 32 rows x 8 chunks
    const int vrow = tid >> 2, vch = tid & 3;   // V: 64 rows x 4 chunks
    uint4 kreg, vreg;

    // stage tile 0 directly, prefetch tile 1 into regs
    {
        const uint4 k0 = *(const uint4*)(k_bf + (size_t)(kbase + krow) * 64 + kch * 8);
        const uint4 v0 = *(const uint4*)(vT_bf + (size_t)vrow * SVT + kbase + vch * 8);
        *(uint4*)(&kt[0][krow * KTS + kch * 8]) = k0;
        *(uint4*)(&vt[0][vrow * VTS + vch * 8]) = v0;
        const int key1 = kbase + 32;
        kreg = *(const uint4*)(k_bf + (size_t)(key1 + krow) * 64 + kch * 8);
        vreg = *(const uint4*)(vT_bf + (size_t)vrow * SVT + key1 + vch * 8);
    }
    __syncthreads();

    const int nIter = krange >> 5;
#pragma unroll 2
    for (int kc = 0; kc < nIter; ++kc) {
        const int cur = kc & 1;
        // write the prefetched tile kc+1 into the other buffer (its readers all
        // finished an entire iteration ago, behind the previous barrier)
        if (kc + 1 < nIter) {
            *(uint4*)(&kt[cur ^ 1][krow * KTS + kch * 8]) = kreg;
            *(uint4*)(&vt[cur ^ 1][vrow * VTS + vch * 8]) = vreg;
        }
        // issue global loads for tile kc+2
        if (kc + 2 < nIter) {
            const int key2 = kbase + (kc + 2) * 32;
            kreg = *(const uint4*)(k_bf + (size_t)(key2 + krow) * 64 + kch * 8);
            vreg = *(const uint4*)(vT_bf + (size_t)vrow * SVT + key2 + vch * 8);
        }
        const unsigned short* ktc = &kt[cur][0];
        const unsigned short* vtc = &vt[cur][0];
        const short8 bE0 = *(const short8*)(ktc + (2 * ln) * KTS + quad * 8);
        const short8 bE1 = *(const short8*)(ktc + (2 * ln) * KTS + 32 + quad * 8);
        const short8 bO0 = *(const short8*)(ktc + (2 * ln + 1) * KTS + quad * 8);
        const short8 bO1 = *(const short8*)(ktc + (2 * ln + 1) * KTS + 32 + quad * 8);
        const short8 v0 = *(const short8*)(vtc + (0 * 16 + ln) * VTS + quad * 8);
        const short8 v1 = *(const short8*)(vtc + (1 * 16 + ln) * VTS + quad * 8);
        const short8 v2 = *(const short8*)(vtc + (2 * 16 + ln) * VTS + quad * 8);
        const short8 v3 = *(const short8*)(vtc + (3 * 16 + ln) * VTS + quad * 8);

        f32x4 scE[4], scO[4];
#pragma unroll
        for (int T = 0; T < 4; ++T) {
            scE[T] = __builtin_amdgcn_mfma_f32_16x16x32_bf16(aQ[T][0], bE0, zero, 0, 0, 0);
            scE[T] = __builtin_amdgcn_mfma_f32_16x16x32_bf16(aQ[T][1], bE1, scE[T], 0, 0, 0);
            scO[T] = __builtin_amdgcn_mfma_f32_16x16x32_bf16(aQ[T][0], bO0, zero, 0, 0, 0);
            scO[T] = __builtin_amdgcn_mfma_f32_16x16x32_bf16(aQ[T][1], bO1, scO[T], 0, 0, 0);
        }
#pragma unroll
        for (int T = 0; T < 4; ++T) {
            unsigned short* w = &pTs[wave][T][0];
#pragma unroll
            for (int r = 0; r < 4; ++r) {
                const float pE = __expf(scE[T][r] * 0.125f);
                const float pO = __expf(scO[T][r] * 0.125f);
                l_acc[T][r] += pE + pO;
                const unsigned int pk = (unsigned int)f2bfu(pE) | ((unsigned int)f2bfu(pO) << 16);
                *(unsigned int*)(w + (quad * 4 + r) * PS + 2 * ln) = pk;
            }
        }
#pragma unroll
        for (int T = 0; T < 4; ++T) {
            const short8 aP = *(const short8*)(&pTs[wave][T][ln * PS + quad * 8]);
            acc[T][0] = __builtin_amdgcn_mfma_f32_16x16x32_bf16(aP, v0, acc[T][0], 0, 0, 0);
            acc[T][1] = __builtin_amdgcn_mfma_f32_16x16x32_bf16(aP, v1, acc[T][1], 0, 0, 0);
            acc[T][2] = __builtin_amdgcn_mfma_f32_16x16x32_bf16(aP, v2, acc[T][2], 0, 0, 0);
            acc[T][3] = __builtin_amdgcn_mfma_f32_16x16x32_bf16(aP, v3, acc[T][3], 0, 0, 0);
        }
        __syncthreads();
    }

    unsigned short* ob = o_split + ((size_t)blockIdx.y * S_LEN + qrow0) * 64;
#pragma unroll
    for (int T = 0; T < 4; ++T) {
#pragma unroll
        for (int r = 0; r < 4; ++r) {
            const int row = 16 * T + quad * 4 + r;
            ob[row * 64 +  0 + ln] = f2bfu(acc[T][0][r]);
            ob[row * 64 + 16 + ln] = f2bfu(acc[T][1][r]);
            ob[row * 64 + 32 + ln] = f2bfu(acc[T][2][r]);
            ob[row * 64 + 48 + ln] = f2bfu(acc[T][3][r]);
        }
#pragma unroll
        for (int r = 0; r < 4; ++r) {
            float v = l_acc[T][r];
            v += __shfl_xor(v, 1); v += __shfl_xor(v, 2);
            v += __shfl_xor(v, 4); v += __shfl_xor(v, 8);
            if (ln == 0)
                l_split[blockIdx.y * S_LEN + qrow0 + 16 * T + quad * 4 + r] = v;
        }
    }
}

// ---------------- Kernel 3: normalize + pool (256 blocks) + last-block finalize ----------------
__global__ __launch_bounds__(256) void norm_final(
    const unsigned short* __restrict__ o_split, const float* __restrict__ l_split,
    float* __restrict__ pool_part, int* __restrict__ counter,
    const float* __restrict__ conv_part,
    const void* __restrict__ Wp, const void* __restrict__ bp,
    const void* __restrict__ x, const void* __restrict__ Wq,
    void* __restrict__ out, int ksplit)
{
    __shared__ float psh[64];
    const int tid = threadIdx.x;
    if (tid < 64) psh[tid] = 0.f;
    __syncthreads();

    const int r = blockIdx.x * 32 + (tid >> 3);
    const int c = (tid & 7) * 8;
    float l = 0.f;
    for (int s = 0; s < ksplit; ++s) l += l_split[s * S_LEN + r];
    float o[8] = {0.f, 0.f, 0.f, 0.f, 0.f, 0.f, 0.f, 0.f};
    for (int s = 0; s < ksplit; ++s) {
        const uint4 v = *(const uint4*)(o_split + ((size_t)s * S_LEN + r) * 64 + c);
        o[0] += bfbits2f(v.x & 0xffff); o[1] += bfbits2f(v.x >> 16);
        o[2] += bfbits2f(v.y & 0xffff); o[3] += bfbits2f(v.y >> 16);
        o[4] += bfbits2f(v.z & 0xffff); o[5] += bfbits2f(v.z >> 16);
        o[6] += bfbits2f(v.w & 0xffff); o[7] += bfbits2f(v.w >> 16);
    }
    const float inv = 1.f / l;
#pragma unroll
    for (int j = 0; j < 8; ++j) atomicAdd(&psh[c + j], o[j] * inv);
    __syncthreads();
    if (tid < 64) pool_part[blockIdx.x * 64 + tid] = psh[tid];
    __threadfence();
    __shared__ int s_last;
    if (tid == 0) s_last = (atomicAdd(counter, 1) == 255) ? 1 : 0;
    __syncthreads();
    if (!s_last) return;
    __threadfence();   // acquire: all 255 other blocks' pool_part writes visible

    // sum 256 block partials: thread t -> elem t&63, block-chunk t>>6
    __shared__ float fsh[256];
    {
        float acc = 0.f;
        const int e = tid & 63, b0 = (tid >> 6) * 64;
        for (int b = b0; b < b0 + 64; ++b) acc += pool_part[b * 64 + e];
        fsh[tid] = acc;
    }
    __syncthreads();
    if (tid >= 64) return;

    const int e = tid;
    const float pe = fsh[e] + fsh[64 + e] + fsh[128 + e] + fsh[192 + e];
    int badx = hw_bad(((const unsigned short*)x)[e]);
    int badw = hw_bad(((const unsigned short*)Wq)[e]);
    const int fx = (__ballot(badx) != 0ULL) ? 1 : 0;
    const int fw = (__ballot(badw) != 0ULL) ? 1 : 0;
    const int out_f32 = fx & fw;

    float cv = conv_part[e];
    cv += __shfl_xor(cv, 1); cv += __shfl_xor(cv, 2); cv += __shfl_xor(cv, 4);
    cv += __shfl_xor(cv, 8); cv += __shfl_xor(cv, 16); cv += __shfl_xor(cv, 32);
    const float conv_feat = cv * (1.f / (float)NCONV);
    const float pooled = pe * (1.f / (float)S_LEN) * conv_feat;
    float p0 = pooled * ldin(Wp, e * 4 + 0, fw);
    float p1 = pooled * ldin(Wp, e * 4 + 1, fw);
    float p2 = pooled * ldin(Wp, e * 4 + 2, fw);
    float p3 = pooled * ldin(Wp, e * 4 + 3, fw);
    for (int off = 32; off > 0; off >>= 1) {
        p0 += __shfl_down(p0, off);
        p1 += __shfl_down(p1, off);
        p2 += __shfl_down(p2, off);
        p3 += __shfl_down(p3, off);
    }
    if (e == 0) {
        const float r0 = p0 + ldin(bp, 0, fw);
        const float r1 = p1 + ldin(bp, 1, fw);
        const float r2 = p2 + ldin(bp, 2, fw);
        const float r3 = p3 + ldin(bp, 3, fw);
        if (out_f32) {
            float* oo = (float*)out;
            oo[0] = r0; oo[1] = r1; oo[2] = r2; oo[3] = r3;
        } else {
            __hip_bfloat16* oo = (__hip_bfloat16*)out;
            oo[0] = __float2bfloat16(r0); oo[1] = __float2bfloat16(r1);
            oo[2] = __float2bfloat16(r2); oo[3] = __float2bfloat16(r3);
        }
    }
}

extern "C" void kernel_launch(void* const* d_in, const int* in_sizes, int n_in,
                              void* d_out, int out_size, void* d_ws, size_t ws_size,
                              hipStream_t stream)
{
    const void* x  = d_in[0];
    const void* cw = d_in[1];
    const void* cb = d_in[2];
    const void* Wq = d_in[3];
    const void* bq = d_in[4];
    const void* Wk = d_in[5];
    const void* bk = d_in[6];
    const void* Wv = d_in[7];
    const void* bv = d_in[8];
    const void* Wp = d_in[9];
    const void* bp = d_in[10];

    // ws layout (f32 idx): conv_part[64] | counter[1]@64 | pool_part[256*64]@128 |
    // l_split[ks*S] | then bf16: o_split[ks*S*64] | q,k[S*64] | vT[64*SVT]
    auto need = [](int ks) -> size_t {
        return (128 + 256 * 64 + (size_t)ks * S_LEN) * 4
             + (size_t)ks * S_LEN * 64 * 2
             + 2 * (size_t)S_LEN * 64 * 2 + (size_t)64 * SVT * 2 + 1024;
    };
    int ksplit = (ws_size >= need(16)) ? 16 : 8;

    float* ws = (float*)d_ws;
    float* conv_part = ws;                        // 64 f32
    int*   counter   = (int*)(ws + 64);           // 1 int
    float* pool_part = ws + 128;                  // 256*64 f32 [block][e]
    float* l_split   = ws + 128 + 256 * 64;       // ks*S f32
    unsigned short* o_split = (unsigned short*)(l_split + (size_t)ksplit * S_LEN);
    unsigned short* q_bf  = o_split + (size_t)ksplit * S_LEN * 64;
    unsigned short* k_bf  = q_bf + (size_t)S_LEN * 64;
    unsigned short* vT_bf = k_bf + (size_t)S_LEN * 64;

    qkv_conv<<<576, 256, 0, stream>>>(x, cw, cb, Wq, bq, Wk, bk, Wv, bv,
                                      q_bf, k_bf, vT_bf, conv_part, counter);
    attn_bf<<<dim3(S_LEN / 256, ksplit), 256, 0, stream>>>(q_bf, k_bf, vT_bf, o_split, l_split,
                                                            S_LEN / ksplit);
    norm_final<<<256, 256, 0, stream>>>(o_split, l_split, pool_part, counter, conv_part,
                                        Wp, bp, x, Wq, d_out, ksplit);
}